// Round 2
// baseline (274.570 us; speedup 1.0000x reference)
//
#include <hip/hip_runtime.h>
#include <math.h>

#define TPB 256

// Fused verblizer:
//  - block stages its x[B0:B0+256, 0:20] slice via fully-coalesced float4 loads,
//    reducing each float4 chunk to (max, argmax) written as uint2 to LDS
//    (token stride 5 pairs = 10 words: b64 access lands at the 4-lane/bank floor)
//  - per-block pu window: 2 binary searches + cooperative flag marking +
//    ballot prefix -> rank per token (replaces 2M global binary searches)
//  - per-token: combine 5 chunk-candidates -> expert idx, Linear(2,2)+softmax,
//    write y[s] and scatter y2[dst], dst = flag ? rank : P + s - rank
__global__ __launch_bounds__(TPB) void verblizer_fused_kernel(
    const float4* __restrict__ x4,   // [S*5] float4 view of x[1,S,20]
    const float2* __restrict__ h2,   // [S]
    const float*  __restrict__ W,    // [20,2,2]
    const float*  __restrict__ b,    // [20,2]
    const int*    __restrict__ pu,   // [P] sorted unique
    float2*       __restrict__ y,    // out1 [S]
    float2*       __restrict__ y2,   // out2 [S]
    int S, int P)
{
    __shared__ float sW[80];
    __shared__ float sb[40];
    __shared__ uint2 pairs[TPB * 5];   // (float bits of chunk max, elem idx 0..19)
    __shared__ int   flags[TPB];
    __shared__ int   r0s, r1s;
    __shared__ int   wsum[TPB / 64];

    const int t  = threadIdx.x;
    const int B0 = blockIdx.x * TPB;
    const int nb = min(TPB, S - B0);

    if (t < 80)       sW[t]      = W[t];
    else if (t < 120) sb[t - 80] = b[t - 80];
    flags[t] = 0;

    // block-boundary ranks: lower_bound(pu, B0) / lower_bound(pu, B0+nb)
    if (t < 2) {
        int target = (t == 0) ? B0 : (B0 + nb);
        int lo = 0, hi = P;
        while (lo < hi) {
            int mid = (lo + hi) >> 1;
            if (pu[mid] < target) lo = mid + 1; else hi = mid;
        }
        if (t == 0) r0s = lo; else r1s = lo;
    }

    // stage x: contiguous float4 loads, per-chunk (max, idx) reduction
    const int nchunk = nb * 5;
    const float4* xb = x4 + (size_t)B0 * 5;
#pragma unroll
    for (int j = 0; j < 5; ++j) {
        int m = t + TPB * j;
        if (m < nchunk) {
            float4 v  = xb[m];
            int   tok = m / 5;
            int   c   = m - 5 * tok;
            float best = v.x; int bi = 0;
            if (v.y > best) { best = v.y; bi = 1; }
            if (v.z > best) { best = v.z; bi = 2; }
            if (v.w > best) { best = v.w; bi = 3; }
            pairs[tok * 5 + c] = make_uint2(__float_as_uint(best), (unsigned)(4 * c + bi));
        }
    }
    __syncthreads();

    // mark this block's pu tokens (coalesced read of the pu slice)
    const int r0 = r0s;
    const int nmark = r1s - r0;
    if (t < nmark) flags[pu[r0 + t] - B0] = 1;
    __syncthreads();

    // ballot prefix over flags -> per-token rank
    const bool f   = (t < nb) && flags[t];
    const unsigned long long mask = __ballot(f);
    const int lane = t & 63;
    const int w    = t >> 6;
    if (lane == 0) wsum[w] = __popcll(mask);
    const int cnt = __popcll(mask & ((1ull << lane) - 1ull));
    __syncthreads();

    if (t >= nb) return;

    int base = 0;
#pragma unroll
    for (int ww = 0; ww < TPB / 64; ++ww)
        if (ww < w) base += wsum[ww];
    const int s    = B0 + t;
    const int rank = r0 + base + cnt;

    // combine 5 chunk candidates (ascending order keeps first-max semantics)
    float best = -INFINITY; int bi = 0;
#pragma unroll
    for (int c = 0; c < 5; ++c) {
        uint2 p = pairs[t * 5 + c];
        float v = __uint_as_float(p.x);
        if (v > best) { best = v; bi = (int)p.y; }
    }

    // Linear(2,2) + softmax(2)
    float2 hv = h2[s];
    const float* we = sW + bi * 4;
    float y0 = fmaf(hv.x, we[0], fmaf(hv.y, we[1], sb[bi * 2 + 0]));
    float y1 = fmaf(hv.x, we[2], fmaf(hv.y, we[3], sb[bi * 2 + 1]));
    float mx = fmaxf(y0, y1);
    float e0 = __expf(y0 - mx);
    float e1 = __expf(y1 - mx);
    float inv = 1.0f / (e0 + e1);
    float2 yo = make_float2(e0 * inv, e1 * inv);

    y[s] = yo;
    const int dst = f ? rank : (P + s - rank);
    y2[dst] = yo;
}

extern "C" void kernel_launch(void* const* d_in, const int* in_sizes, int n_in,
                              void* d_out, int out_size, void* d_ws, size_t ws_size,
                              hipStream_t stream) {
    const float* x  = (const float*)d_in[0];   // [1,S,20]
    const float* h  = (const float*)d_in[1];   // [S,2]
    const float* W  = (const float*)d_in[2];   // [20,2,2]
    const float* b  = (const float*)d_in[3];   // [20,2]
    const int*   pu = (const int*)d_in[4];     // [P]

    const int S = in_sizes[1] / 2;
    const int P = in_sizes[4];

    float2* y  = (float2*)d_out;
    float2* y2 = (float2*)d_out + S;

    const int grid = (S + TPB - 1) / TPB;
    verblizer_fused_kernel<<<grid, TPB, 0, stream>>>(
        (const float4*)x, (const float2*)h, W, b, pu, y, y2, S, P);
}

// Round 3
// 254.965 us; speedup vs baseline: 1.0769x; 1.0769x over previous
//
#include <hip/hip_runtime.h>
#include <math.h>
#include <limits.h>

#define TPB 256   // must equal tile size (boundary kernel uses >>8)

// K1: boundary[b] = lower_bound(pu, 256*b) for b in [0, NB], computed by
// inversion (no binary search): pu[i] is the answer for all b with
// 256b in (pu[i-1], pu[i]].
__global__ __launch_bounds__(TPB) void boundary_kernel(
    const int* __restrict__ pu, int P, int NB, int* __restrict__ boundary)
{
    int i = blockIdx.x * TPB + threadIdx.x;
    if (i >= P) return;
    int cur  = pu[i];
    int lo   = (i == 0) ? 0 : (pu[i - 1] >> 8) + 1;
    int hi   = cur >> 8;                       // inclusive
    for (int b = lo; b <= hi; ++b) boundary[b] = i;
    if (i == P - 1)
        for (int b = hi + 1; b <= NB; ++b) boundary[b] = P;
}

// K2: fused verblizer. Per 256-token tile:
//  - r0,r1 from boundary[] (uniform scalar loads, no search)
//  - pu-slice gather issued immediately, overlapped with x staging
//  - coalesced float4 x staging -> per-chunk (max,argmax) pairs in LDS
//  - ballot-prefix rank -> scatter destination
__global__ __launch_bounds__(TPB) void verblizer_fused_kernel(
    const float4* __restrict__ x4,   // [S*5] float4 view of x[1,S,20]
    const float2* __restrict__ h2,   // [S]
    const float*  __restrict__ W,    // [20,2,2]
    const float*  __restrict__ b,    // [20,2]
    const int*    __restrict__ pu,   // [P] sorted unique
    const int*    __restrict__ boundary, // [NB+1]
    float2*       __restrict__ y,    // out1 [S]
    float2*       __restrict__ y2,   // out2 [S]
    int S, int P)
{
    __shared__ float sW[80];
    __shared__ float sb[40];
    __shared__ uint2 pairs[TPB * 5];
    __shared__ int   flags[TPB];
    __shared__ int   wsum[TPB / 64];

    const int t  = threadIdx.x;
    const int bk = blockIdx.x;
    const int B0 = bk * TPB;
    const int nb = min(TPB, S - B0);

    // uniform (scalar) boundary loads — no search
    const int r0 = boundary[bk];
    const int r1 = boundary[bk + 1];

    // issue the pu-slice gather early (overlaps x staging below)
    const int pv = (t < r1 - r0) ? pu[r0 + t] : -1;

    // prefetch h early
    const int s_clamped = min(B0 + t, S - 1);
    const float2 hv = h2[s_clamped];

    if (t < 80)       sW[t]      = W[t];
    else if (t < 120) sb[t - 80] = b[t - 80];
    flags[t] = 0;

    // stage x: contiguous float4 loads, per-chunk (max, idx) reduction
    const int nchunk = nb * 5;
    const float4* xb = x4 + (size_t)B0 * 5;
#pragma unroll
    for (int j = 0; j < 5; ++j) {
        int m = t + TPB * j;
        if (m < nchunk) {
            float4 v  = xb[m];
            int   tok = m / 5;
            int   c   = m - 5 * tok;
            float best = v.x; int bi = 0;
            if (v.y > best) { best = v.y; bi = 1; }
            if (v.z > best) { best = v.z; bi = 2; }
            if (v.w > best) { best = v.w; bi = 3; }
            pairs[tok * 5 + c] = make_uint2(__float_as_uint(best), (unsigned)(4 * c + bi));
        }
    }
    __syncthreads();

    // mark this block's pu tokens
    if (pv >= 0) flags[pv - B0] = 1;
    __syncthreads();

    // ballot prefix over flags -> per-token rank
    const bool f   = (t < nb) && flags[t];
    const unsigned long long mask = __ballot(f);
    const int lane = t & 63;
    const int w    = t >> 6;
    if (lane == 0) wsum[w] = __popcll(mask);
    const int cnt = __popcll(mask & ((1ull << lane) - 1ull));
    __syncthreads();

    if (t >= nb) return;

    int base = 0;
#pragma unroll
    for (int ww = 0; ww < TPB / 64; ++ww)
        if (ww < w) base += wsum[ww];
    const int s    = B0 + t;
    const int rank = r0 + base + cnt;

    // combine 5 chunk candidates (ascending c keeps first-max semantics)
    float best = -INFINITY; int bi = 0;
#pragma unroll
    for (int c = 0; c < 5; ++c) {
        uint2 p = pairs[t * 5 + c];
        float v = __uint_as_float(p.x);
        if (v > best) { best = v; bi = (int)p.y; }
    }

    // Linear(2,2) + softmax(2)
    const float* we = sW + bi * 4;
    float y0 = fmaf(hv.x, we[0], fmaf(hv.y, we[1], sb[bi * 2 + 0]));
    float y1 = fmaf(hv.x, we[2], fmaf(hv.y, we[3], sb[bi * 2 + 1]));
    float mx = fmaxf(y0, y1);
    float e0 = __expf(y0 - mx);
    float e1 = __expf(y1 - mx);
    float inv = 1.0f / (e0 + e1);
    float2 yo = make_float2(e0 * inv, e1 * inv);

    y[s] = yo;
    const int dst = f ? rank : (P + s - rank);
    y2[dst] = yo;
}

extern "C" void kernel_launch(void* const* d_in, const int* in_sizes, int n_in,
                              void* d_out, int out_size, void* d_ws, size_t ws_size,
                              hipStream_t stream) {
    const float* x  = (const float*)d_in[0];   // [1,S,20]
    const float* h  = (const float*)d_in[1];   // [S,2]
    const float* W  = (const float*)d_in[2];   // [20,2,2]
    const float* b  = (const float*)d_in[3];   // [20,2]
    const int*   pu = (const int*)d_in[4];     // [P]

    const int S  = in_sizes[1] / 2;
    const int P  = in_sizes[4];
    const int NB = (S + TPB - 1) / TPB;        // number of tiles

    int* boundary = (int*)d_ws;                // NB+1 ints

    float2* y  = (float2*)d_out;
    float2* y2 = (float2*)d_out + S;

    boundary_kernel<<<(P + TPB - 1) / TPB, TPB, 0, stream>>>(pu, P, NB, boundary);
    verblizer_fused_kernel<<<NB, TPB, 0, stream>>>(
        (const float4*)x, (const float2*)h, W, b, pu, boundary, y, y2, S, P);
}

// Round 4
// 253.609 us; speedup vs baseline: 1.0827x; 1.0053x over previous
//
#include <hip/hip_runtime.h>
#include <math.h>

#define TPB  256
#define TILE 512          // tokens per block (2 per thread)
#define GRAN 128          // boundary granularity in tokens

// K1: boundary[b] = lower_bound(pu, GRAN*b), computed by inversion (no search).
__global__ __launch_bounds__(TPB) void boundary_kernel(
    const int* __restrict__ pu, int P, int NB, int* __restrict__ boundary)
{
    int i = blockIdx.x * TPB + threadIdx.x;
    if (i >= P) return;
    int cur = pu[i];
    int lo  = (i == 0) ? 0 : (pu[i - 1] / GRAN) + 1;
    int hi  = cur / GRAN;                     // inclusive
    for (int bb = lo; bb <= hi; ++bb) boundary[bb] = i;
    if (i == P - 1)
        for (int bb = hi + 1; bb <= NB; ++bb) boundary[bb] = P;
}

// K2: fused verblizer, 512-token tiles, all global loads issued up-front.
__global__ __launch_bounds__(TPB) void verblizer_fused_kernel(
    const float4* __restrict__ x4,   // [S*5] float4 view of x[1,S,20]
    const float2* __restrict__ h2,   // [S]
    const float*  __restrict__ W,    // [20,2,2]
    const float*  __restrict__ b,    // [20,2]
    const int*    __restrict__ pu,   // [P] sorted unique
    const int*    __restrict__ boundary,
    float2*       __restrict__ y,    // out1 [S]
    float2*       __restrict__ y2,   // out2 [S]
    int S, int P)
{
    __shared__ __align__(16) uint2 pairs[TILE * 6];  // 5 chunks + (-inf) pad
    __shared__ unsigned char flags[TILE];
    __shared__ int   wsum[TILE / 64];
    __shared__ float sW[80];
    __shared__ float sb[40];

    const int t  = threadIdx.x;
    const int B0 = min((int)blockIdx.x * TILE, S - TILE);  // full blocks only;
    // overlapping blocks recompute identical values -> identical writes (safe)

    // uniform boundary loads (scalar path), issued first
    const int r0 = boundary[B0 / GRAN];
    const int r1 = boundary[(B0 + TILE) / GRAN];
    const int nmark = r1 - r0;

    // ---- issue ALL global loads before any use (max MLP) ----
    float4 xv[10];
    const float4* xb = x4 + (size_t)B0 * 5;
#pragma unroll
    for (int j = 0; j < 10; ++j) xv[j] = xb[t + TPB * j];
    const float2 hA = h2[B0 + t];
    const float2 hB = h2[B0 + TPB + t];
    const int pv0 = (t < nmark)       ? pu[r0 + t]       : -1;
    const int pv1 = (TPB + t < nmark) ? pu[r0 + TPB + t] : -1;

    if (t < 80)       sW[t]      = W[t];
    else if (t < 120) sb[t - 80] = b[t - 80];
    flags[t]       = 0;
    flags[TPB + t] = 0;
    pairs[t * 6 + 5]         = make_uint2(0xFF800000u, 0u);  // -inf pad
    pairs[(TPB + t) * 6 + 5] = make_uint2(0xFF800000u, 0u);

    // reduce each float4 chunk -> (max, idx) pair in LDS
#pragma unroll
    for (int j = 0; j < 10; ++j) {
        int m   = t + TPB * j;
        int tok = m / 5;
        int c   = m - 5 * tok;
        float4 v = xv[j];
        float best = v.x; int bi = 0;
        if (v.y > best) { best = v.y; bi = 1; }
        if (v.z > best) { best = v.z; bi = 2; }
        if (v.w > best) { best = v.w; bi = 3; }
        pairs[tok * 6 + c] = make_uint2(__float_as_uint(best), (unsigned)(4 * c + bi));
    }
    __syncthreads();

    if (pv0 >= 0) flags[pv0 - B0] = 1;
    if (pv1 >= 0) flags[pv1 - B0] = 1;
    __syncthreads();

    // ballot prefix over 512 flags (8 wave-segments of 64)
    const int lane = t & 63;
    const int w    = t >> 6;
    const bool fA = flags[t] != 0;
    const bool fB = flags[TPB + t] != 0;
    const unsigned long long mA = __ballot(fA);
    const unsigned long long mB = __ballot(fB);
    if (lane == 0) { wsum[w] = __popcll(mA); wsum[4 + w] = __popcll(mB); }
    const unsigned long long lmask = (1ull << lane) - 1ull;
    const int cA = __popcll(mA & lmask);
    const int cB = __popcll(mB & lmask);
    __syncthreads();

    int baseA = 0, baseB = 0;
#pragma unroll
    for (int ww = 0; ww < 8; ++ww) {
        int v = wsum[ww];
        if (ww < w)     baseA += v;
        if (ww < 4 + w) baseB += v;
    }
    const int rankA = r0 + baseA + cA;
    const int rankB = r0 + baseB + cB;

    // per-token epilogue: argmax combine, Linear(2,2)+softmax, 2 stores
#pragma unroll
    for (int half = 0; half < 2; ++half) {
        const int  tl   = half ? (TPB + t) : t;
        const float2 hv = half ? hB : hA;
        const bool f    = half ? fB : fA;
        const int  rank = half ? rankB : rankA;

        const uint4* pp = (const uint4*)&pairs[tl * 6];  // 48B-aligned
        uint4 q0 = pp[0], q1 = pp[1], q2 = pp[2];
        float best = -INFINITY; int bi = 0;
        {
            float v;
            v = __uint_as_float(q0.x); if (v > best) { best = v; bi = (int)q0.y; }
            v = __uint_as_float(q0.z); if (v > best) { best = v; bi = (int)q0.w; }
            v = __uint_as_float(q1.x); if (v > best) { best = v; bi = (int)q1.y; }
            v = __uint_as_float(q1.z); if (v > best) { best = v; bi = (int)q1.w; }
            v = __uint_as_float(q2.x); if (v > best) { best = v; bi = (int)q2.y; }
            v = __uint_as_float(q2.z); if (v > best) { best = v; bi = (int)q2.w; }
        }

        const float* we = sW + bi * 4;
        float y0 = fmaf(hv.x, we[0], fmaf(hv.y, we[1], sb[bi * 2 + 0]));
        float y1 = fmaf(hv.x, we[2], fmaf(hv.y, we[3], sb[bi * 2 + 1]));
        float mx = fmaxf(y0, y1);
        float e0 = __expf(y0 - mx);
        float e1 = __expf(y1 - mx);
        float inv = 1.0f / (e0 + e1);
        float2 yo = make_float2(e0 * inv, e1 * inv);

        const int s = B0 + tl;
        y[s] = yo;
        const int dst = f ? rank : (P + s - rank);
        y2[dst] = yo;
    }
}

extern "C" void kernel_launch(void* const* d_in, const int* in_sizes, int n_in,
                              void* d_out, int out_size, void* d_ws, size_t ws_size,
                              hipStream_t stream) {
    const float* x  = (const float*)d_in[0];   // [1,S,20]
    const float* h  = (const float*)d_in[1];   // [S,2]
    const float* W  = (const float*)d_in[2];   // [20,2,2]
    const float* b  = (const float*)d_in[3];   // [20,2]
    const int*   pu = (const int*)d_in[4];     // [P]

    const int S  = in_sizes[1] / 2;
    const int P  = in_sizes[4];
    const int NB = S / GRAN;                   // S divisible by 128

    int* boundary = (int*)d_ws;                // NB+1 ints

    float2* y  = (float2*)d_out;
    float2* y2 = (float2*)d_out + S;

    boundary_kernel<<<(P + TPB - 1) / TPB, TPB, 0, stream>>>(pu, P, NB, boundary);

    const int grid = (S + TILE - 1) / TILE;
    verblizer_fused_kernel<<<grid, TPB, 0, stream>>>(
        (const float4*)x, (const float2*)h, W, b, pu, boundary, y, y2, S, P);
}